// Round 5
// baseline (1259.334 us; speedup 1.0000x reference)
//
#include <hip/hip_runtime.h>
#include <math.h>

constexpr int BT = 65536;
constexpr int D  = 256;
constexpr int E  = 64;
constexpr int K  = 2048;
constexpr int J  = 512; // 2*D

// d_out layout (floats): res | topk_idx | topk_scores | counts
constexpr size_t OFF_IDX = (size_t)BT * D * 2;       // 33,554,432
constexpr size_t OFF_SCR = OFF_IDX + (size_t)E * K;  // +131,072
constexpr size_t OFF_CNT = OFF_SCR + (size_t)E * K;  // +131,072

// ---------------------------------------------------------------------------
// K1: scoresT[e][t] = fp32 dot as ONE sequential FMA chain j=0..511
// (single-accumulator; the MKL-large-kc / ARM-OpenBLAS-large-Q sgemm scheme).
// ---------------------------------------------------------------------------
__global__ __launch_bounds__(256)
void k1_scores(const float* __restrict__ x, const float* __restrict__ gw,
               float* __restrict__ scoresT) {
  __shared__ float xs[64][65];
  __shared__ float gs[64][68];
  const int t0 = blockIdx.x * 64;
  const int tid = threadIdx.x;
  const int tx = tid & 15;   // token sub-index
  const int ty = tid >> 4;   // expert group (4 experts per thread)
  float acc[4][4] = {};      // single chain j = 0..511

#define K1_STAGE(kk)                                                        \
  for (int i = tid; i < 4096; i += 256) {                                   \
    int r = i >> 6, c = i & 63;                                             \
    xs[r][c] = x[(size_t)(t0 + r) * J + (kk) * 64 + c];                     \
    gs[r][c] = gw[(size_t)((kk) * 64 + r) * E + c];                         \
  }                                                                         \
  __syncthreads();

#define K1_INNER(ACC)                                                       \
  _Pragma("unroll 16")                                                      \
  for (int j = 0; j < 64; ++j) {                                            \
    float xv[4], gv[4];                                                     \
    _Pragma("unroll") for (int a = 0; a < 4; ++a) xv[a] = xs[a*16+tx][j];   \
    _Pragma("unroll") for (int b = 0; b < 4; ++b) gv[b] = gs[j][ty*4+b];    \
    _Pragma("unroll") for (int a = 0; a < 4; ++a)                           \
      _Pragma("unroll") for (int b = 0; b < 4; ++b)                         \
        ACC[a][b] = fmaf(xv[a], gv[b], ACC[a][b]);                          \
  }                                                                         \
  __syncthreads();

  for (int kk = 0; kk < 8; ++kk) { K1_STAGE(kk) K1_INNER(acc) }

#pragma unroll
  for (int b = 0; b < 4; ++b) {
    int e = ty * 4 + b;
#pragma unroll
    for (int a = 0; a < 4; ++a)
      scoresT[(size_t)e * BT + t0 + a * 16 + tx] = acc[a][b];
  }
}

// ---------------------------------------------------------------------------
// K2: per-expert top-K on fp32 scores (descending; ties -> lower index,
// stable). Radix-select + bitonic sort of (score_u32 << 32 | ~idx).
// ---------------------------------------------------------------------------
__device__ __forceinline__ unsigned fkey(float s) {
  unsigned u = __float_as_uint(s);
  return (u & 0x80000000u) ? ~u : (u | 0x80000000u);
}

__global__ __launch_bounds__(1024)
void k2_topk(const float* __restrict__ scoresT, float* __restrict__ o_idx,
             float* __restrict__ o_scr, float* __restrict__ o_cnt) {
  const int e = blockIdx.x;
  const float* row = scoresT + (size_t)e * BT;
  __shared__ unsigned hist[16][256];  // per-wave sub-histograms
  __shared__ unsigned sh_need, sh_prefix;
  __shared__ int sh_n;
  __shared__ unsigned long long keys[4096];
  const int tid = threadIdx.x;
  const int wv = tid >> 6;

  unsigned mask = 0u, prefix = 0u, need = (unsigned)K;
  for (int pass = 0; pass < 4; ++pass) {
    const int shift = 24 - 8 * pass;
    for (int i = tid; i < 16 * 256; i += 1024) ((unsigned*)hist)[i] = 0u;
    __syncthreads();
    for (int i = tid; i < BT; i += 1024) {
      unsigned u = fkey(row[i]);
      if ((u & mask) == prefix) atomicAdd(&hist[wv][(u >> shift) & 0xFFu], 1u);
    }
    __syncthreads();
    if (tid < 256) {
      unsigned s = 0;
#pragma unroll
      for (int w = 0; w < 16; ++w) s += hist[w][tid];
      hist[0][tid] = s;
    }
    __syncthreads();
    if (tid == 0) {
      unsigned cum = 0u; int b = 0;
      for (int v = 255; v >= 0; --v) {
        unsigned h = hist[0][v];
        if (cum + h >= need) { b = v; break; }
        cum += h;
      }
      sh_need = need - cum;
      sh_prefix = prefix | ((unsigned)b << shift);
    }
    __syncthreads();
    need = sh_need;
    prefix = sh_prefix;
    mask |= (0xFFu << shift);
    __syncthreads();
  }
  const unsigned u_thr = prefix;  // exact K-th key value
  if (tid == 0) sh_n = 0;
  __syncthreads();
  for (int i = tid; i < BT; i += 1024) {
    unsigned u = fkey(row[i]);
    if (u >= u_thr) {
      int pos = atomicAdd(&sh_n, 1);
      if (pos < 4096)
        keys[pos] = ((unsigned long long)u << 32) | (unsigned)(~(unsigned)i);
    }
  }
  __syncthreads();
  int n = sh_n; if (n > 4096) n = 4096;
  for (int i = n + tid; i < 4096; i += 1024) keys[i] = 0ull;
  __syncthreads();
  // bitonic sort, descending: (score desc, then idx asc via ~idx desc)
  for (int kk = 2; kk <= 4096; kk <<= 1) {
    for (int j = kk >> 1; j > 0; j >>= 1) {
      for (int i = tid; i < 4096; i += 1024) {
        int ij = i ^ j;
        if (ij > i) {
          bool up = ((i & kk) == 0);
          unsigned long long a = keys[i], b = keys[ij];
          if ((a < b) == up) { keys[i] = b; keys[ij] = a; }
        }
      }
      __syncthreads();
    }
  }
  for (int r = tid; r < K; r += 1024) {
    unsigned long long kv = keys[r];
    unsigned u = (unsigned)(kv >> 32);
    unsigned idx = ~((unsigned)kv);
    float s = __uint_as_float((u & 0x80000000u) ? (u ^ 0x80000000u) : ~u);
    o_idx[(size_t)e * K + r] = (float)idx;
    o_scr[(size_t)e * K + r] = s;
    atomicAdd(&o_cnt[idx], 1.0f);
  }
}

// ---------------------------------------------------------------------------
// K4: per-expert complex GEMM as real GEMM M=2048,N=512,K=512 with derived B:
//   A[k][j] = x[t_k][j]           (j = 2d+ci)
//   B[j][2f+co] = ew[e][d][f][ci^co] * ((ci==1 && co==0) ? -1 : 1)
// Epilogue: atomicAdd(out[t_k][col], w_k * y). 64x64 tile, 256 thr, 4x4 micro.
// ---------------------------------------------------------------------------
__global__ __launch_bounds__(256)
void k4_gemm(const float* __restrict__ x, const float* __restrict__ ew,
             const float* __restrict__ o_idx, const float* __restrict__ o_scr,
             float* __restrict__ out) {
  const int e  = blockIdx.z;
  const int km = blockIdx.y;  // row tile (0..31)
  const int fn = blockIdx.x;  // col tile (0..7)
  __shared__ float As[64][36];
  __shared__ float Bs[32][66];
  __shared__ int   tIdx[64];
  __shared__ float wRow[64];
  const int tid = threadIdx.x;
  if (tid < 64) {
    size_t gi = (size_t)e * K + km * 64 + tid;
    tIdx[tid] = (int)o_idx[gi];
    wRow[tid] = o_scr[gi];
  }
  __syncthreads();
  const int tx = tid & 15, ty = tid >> 4;
  float acc[4][4] = {};

  for (int kk = 0; kk < J; kk += 32) {
    {  // stage A: 64 rows x 32 cols via float4 (gathered rows)
      int f4 = tid & 7;
      int r  = tid >> 3;  // 0..31
      *(float4*)(&As[r][f4 * 4]) =
          *(const float4*)(x + (size_t)tIdx[r] * J + kk + f4 * 4);
      *(float4*)(&As[r + 32][f4 * 4]) =
          *(const float4*)(x + (size_t)tIdx[r + 32] * J + kk + f4 * 4);
    }
#pragma unroll
    for (int it = 0; it < 8; ++it) {  // stage B: 32 x 64
      int lin = tid + it * 256;
      int j = lin >> 6, col = lin & 63;
      int jj = kk + j;
      int d = jj >> 1, ci = jj & 1;
      int f = (fn * 64 + col) >> 1, co = col & 1;
      float v = ew[((((size_t)e * 256 + d) * 256 + f) << 1) + (ci ^ co)];
      if (ci & (co ^ 1)) v = -v;
      Bs[j][col] = v;
    }
    __syncthreads();
#pragma unroll
    for (int j = 0; j < 32; ++j) {
      float av[4], bv[4];
#pragma unroll
      for (int a = 0; a < 4; ++a) av[a] = As[a * 16 + ty][j];
#pragma unroll
      for (int b = 0; b < 4; ++b) bv[b] = Bs[j][b * 16 + tx];
#pragma unroll
      for (int a = 0; a < 4; ++a)
#pragma unroll
        for (int b = 0; b < 4; ++b) acc[a][b] += av[a] * bv[b];
    }
    __syncthreads();
  }
#pragma unroll
  for (int a = 0; a < 4; ++a) {
    int r = a * 16 + ty;
    int t = tIdx[r];
    float w = wRow[r];
    float* dst = out + (size_t)t * J + fn * 64;
#pragma unroll
    for (int b = 0; b < 4; ++b) atomicAdd(dst + b * 16 + tx, acc[a][b] * w);
  }
}

// ---------------------------------------------------------------------------
// K5: res = gelu(out / max(counts,1) + bias[f]), exact erf, in place, float4.
// ---------------------------------------------------------------------------
__global__ __launch_bounds__(256)
void k5_final(float* __restrict__ res, const float* __restrict__ cnt,
              const float* __restrict__ bias) {
  const int total4 = BT * J / 4;
  for (int i = blockIdx.x * blockDim.x + threadIdx.x; i < total4;
       i += gridDim.x * blockDim.x) {
    float4 v = reinterpret_cast<float4*>(res)[i];
    int base = i << 2;
    int t = base >> 9;
    int col = base & 511;
    float inv = 1.0f / fmaxf(cnt[t], 1.0f);
    int f0 = col >> 1;
    float b0 = bias[f0], b1 = bias[f0 + 1];
    float h0 = v.x * inv + b0;
    float h1 = v.y * inv + b0;
    float h2 = v.z * inv + b1;
    float h3 = v.w * inv + b1;
    const float is2 = 0.70710678118654752f;
    v.x = 0.5f * h0 * (1.0f + erff(h0 * is2));
    v.y = 0.5f * h1 * (1.0f + erff(h1 * is2));
    v.z = 0.5f * h2 * (1.0f + erff(h2 * is2));
    v.w = 0.5f * h3 * (1.0f + erff(h3 * is2));
    reinterpret_cast<float4*>(res)[i] = v;
  }
}

// ---------------------------------------------------------------------------
extern "C" void kernel_launch(void* const* d_in, const int* in_sizes, int n_in,
                              void* d_out, int out_size, void* d_ws,
                              size_t ws_size, hipStream_t stream) {
  const float* x    = (const float*)d_in[0];
  const float* gw   = (const float*)d_in[1];
  const float* ew   = (const float*)d_in[2];
  const float* bias = (const float*)d_in[3];

  float* out_f = (float*)d_out;
  float* res   = out_f;
  float* o_idx = out_f + OFF_IDX;
  float* o_scr = out_f + OFF_SCR;
  float* o_cnt = out_f + OFF_CNT;

  // scoresT (E x BT floats, 16 MiB) borrows the res region until top-k done.
  float* scoresT = res;

  hipMemsetAsync(o_cnt, 0, (size_t)BT * sizeof(float), stream);
  k1_scores<<<BT / 64, 256, 0, stream>>>(x, gw, scoresT);
  k2_topk<<<E, 1024, 0, stream>>>(scoresT, o_idx, o_scr, o_cnt);
  hipMemsetAsync(res, 0, (size_t)BT * J * sizeof(float), stream);
  k4_gemm<<<dim3(8, K / 64, E), 256, 0, stream>>>(x, ew, o_idx, o_scr, res);
  k5_final<<<8192, 256, 0, stream>>>(res, o_cnt, bias);
}

// Round 6
// 655.624 us; speedup vs baseline: 1.9208x; 1.9208x over previous
//
#include <hip/hip_runtime.h>
#include <math.h>

constexpr int BT = 65536;
constexpr int D  = 256;
constexpr int E  = 64;
constexpr int K  = 2048;
constexpr int J  = 512; // 2*D

// d_out layout (floats): res | topk_idx | topk_scores | counts
constexpr size_t OFF_IDX = (size_t)BT * D * 2;       // 33,554,432
constexpr size_t OFF_SCR = OFF_IDX + (size_t)E * K;  // +131,072
constexpr size_t OFF_CNT = OFF_SCR + (size_t)E * K;  // +131,072

typedef __attribute__((ext_vector_type(8))) short bf16x8;
typedef __attribute__((ext_vector_type(4))) float f32x4;

// ---------------------------------------------------------------------------
// K1: scoresT[e][t] = fp32 dot as ONE sequential FMA chain j=0..511
// (bit-matches the np reference's sgemm scheme — DO NOT CHANGE).
// ---------------------------------------------------------------------------
__global__ __launch_bounds__(256)
void k1_scores(const float* __restrict__ x, const float* __restrict__ gw,
               float* __restrict__ scoresT) {
  __shared__ float xs[64][65];
  __shared__ float gs[64][68];
  const int t0 = blockIdx.x * 64;
  const int tid = threadIdx.x;
  const int tx = tid & 15;   // token sub-index
  const int ty = tid >> 4;   // expert group (4 experts per thread)
  float acc[4][4] = {};      // single chain j = 0..511

#define K1_STAGE(kk)                                                        \
  for (int i = tid; i < 4096; i += 256) {                                   \
    int r = i >> 6, c = i & 63;                                             \
    xs[r][c] = x[(size_t)(t0 + r) * J + (kk) * 64 + c];                     \
    gs[r][c] = gw[(size_t)((kk) * 64 + r) * E + c];                         \
  }                                                                         \
  __syncthreads();

#define K1_INNER(ACC)                                                       \
  _Pragma("unroll 16")                                                      \
  for (int j = 0; j < 64; ++j) {                                            \
    float xv[4], gv[4];                                                     \
    _Pragma("unroll") for (int a = 0; a < 4; ++a) xv[a] = xs[a*16+tx][j];   \
    _Pragma("unroll") for (int b = 0; b < 4; ++b) gv[b] = gs[j][ty*4+b];    \
    _Pragma("unroll") for (int a = 0; a < 4; ++a)                           \
      _Pragma("unroll") for (int b = 0; b < 4; ++b)                         \
        ACC[a][b] = fmaf(xv[a], gv[b], ACC[a][b]);                          \
  }                                                                         \
  __syncthreads();

  for (int kk = 0; kk < 8; ++kk) { K1_STAGE(kk) K1_INNER(acc) }

#pragma unroll
  for (int b = 0; b < 4; ++b) {
    int e = ty * 4 + b;
#pragma unroll
    for (int a = 0; a < 4; ++a)
      scoresT[(size_t)e * BT + t0 + a * 16 + tx] = acc[a][b];
  }
}

// ---------------------------------------------------------------------------
// K2: per-expert top-K on fp32 scores (descending; ties -> lower index,
// stable). Radix-select + bitonic sort of (score_u32 << 32 | ~idx).
// Verified passing — DO NOT CHANGE.
// ---------------------------------------------------------------------------
__device__ __forceinline__ unsigned fkey(float s) {
  unsigned u = __float_as_uint(s);
  return (u & 0x80000000u) ? ~u : (u | 0x80000000u);
}

__global__ __launch_bounds__(1024)
void k2_topk(const float* __restrict__ scoresT, float* __restrict__ o_idx,
             float* __restrict__ o_scr, float* __restrict__ o_cnt) {
  const int e = blockIdx.x;
  const float* row = scoresT + (size_t)e * BT;
  __shared__ unsigned hist[16][256];  // per-wave sub-histograms
  __shared__ unsigned sh_need, sh_prefix;
  __shared__ int sh_n;
  __shared__ unsigned long long keys[4096];
  const int tid = threadIdx.x;
  const int wv = tid >> 6;

  unsigned mask = 0u, prefix = 0u, need = (unsigned)K;
  for (int pass = 0; pass < 4; ++pass) {
    const int shift = 24 - 8 * pass;
    for (int i = tid; i < 16 * 256; i += 1024) ((unsigned*)hist)[i] = 0u;
    __syncthreads();
    for (int i = tid; i < BT; i += 1024) {
      unsigned u = fkey(row[i]);
      if ((u & mask) == prefix) atomicAdd(&hist[wv][(u >> shift) & 0xFFu], 1u);
    }
    __syncthreads();
    if (tid < 256) {
      unsigned s = 0;
#pragma unroll
      for (int w = 0; w < 16; ++w) s += hist[w][tid];
      hist[0][tid] = s;
    }
    __syncthreads();
    if (tid == 0) {
      unsigned cum = 0u; int b = 0;
      for (int v = 255; v >= 0; --v) {
        unsigned h = hist[0][v];
        if (cum + h >= need) { b = v; break; }
        cum += h;
      }
      sh_need = need - cum;
      sh_prefix = prefix | ((unsigned)b << shift);
    }
    __syncthreads();
    need = sh_need;
    prefix = sh_prefix;
    mask |= (0xFFu << shift);
    __syncthreads();
  }
  const unsigned u_thr = prefix;  // exact K-th key value
  if (tid == 0) sh_n = 0;
  __syncthreads();
  for (int i = tid; i < BT; i += 1024) {
    unsigned u = fkey(row[i]);
    if (u >= u_thr) {
      int pos = atomicAdd(&sh_n, 1);
      if (pos < 4096)
        keys[pos] = ((unsigned long long)u << 32) | (unsigned)(~(unsigned)i);
    }
  }
  __syncthreads();
  int n = sh_n; if (n > 4096) n = 4096;
  for (int i = n + tid; i < 4096; i += 1024) keys[i] = 0ull;
  __syncthreads();
  // bitonic sort, descending: (score desc, then idx asc via ~idx desc)
  for (int kk = 2; kk <= 4096; kk <<= 1) {
    for (int j = kk >> 1; j > 0; j >>= 1) {
      for (int i = tid; i < 4096; i += 1024) {
        int ij = i ^ j;
        if (ij > i) {
          bool up = ((i & kk) == 0);
          unsigned long long a = keys[i], b = keys[ij];
          if ((a < b) == up) { keys[i] = b; keys[ij] = a; }
        }
      }
      __syncthreads();
    }
  }
  for (int r = tid; r < K; r += 1024) {
    unsigned long long kv = keys[r];
    unsigned u = (unsigned)(kv >> 32);
    unsigned idx = ~((unsigned)kv);
    float s = __uint_as_float((u & 0x80000000u) ? (u ^ 0x80000000u) : ~u);
    o_idx[(size_t)e * K + r] = (float)idx;
    o_scr[(size_t)e * K + r] = s;
    atomicAdd(&o_cnt[idx], 1.0f);
  }
}

// ---------------------------------------------------------------------------
// K4 (MFMA bf16): per-expert real GEMM M=2048,N=512,K=512.
//   A[m][k] = x[tIdx[m]][k]
//   B[k=2d+ci][n=2f+co] = ew[e][d][f][ci^co] * ((ci==1 && co==0) ? -1 : 1)
// 128x128 tile, 4 waves x (64x64 via 4x4 mfma_f32_16x16x32_bf16 frags),
// K-step 64. fp32->bf16 reg-staged into XOR-swizzled LDS (16B-chunk swizzle
// chunk^=(row&7) kills the 16-way ds_read_b128 bank conflict).
// Epilogue: atomicAdd(out[t][col], w * acc).
// ---------------------------------------------------------------------------
__device__ __forceinline__ unsigned short f2bf(float f) {
  unsigned u = __float_as_uint(f);
  u = (u + 0x7FFFu + ((u >> 16) & 1u)) >> 16;  // RTNE
  return (unsigned short)u;
}

__global__ __launch_bounds__(256)
void k4_mfma(const float* __restrict__ x, const float* __restrict__ ew,
             const float* __restrict__ o_idx, const float* __restrict__ o_scr,
             float* __restrict__ out) {
  const int e  = blockIdx.z;
  const int km = blockIdx.y;  // M tile (0..15), 128 rows
  const int fn = blockIdx.x;  // N tile (0..3), 128 cols
  __shared__ __align__(16) unsigned short As[128 * 64];  // [row][chunk sw]
  __shared__ __align__(16) unsigned short Bs[128 * 64];  // [n][chunk sw]
  __shared__ int   tIdx[128];
  __shared__ float wRow[128];
  const int tid = threadIdx.x;
  if (tid < 128) {
    size_t gi = (size_t)e * K + km * 128 + tid;
    tIdx[tid] = (int)o_idx[gi];
    wRow[tid] = o_scr[gi];
  }
  __syncthreads();

  const int lane = tid & 63;
  const int w    = tid >> 6;        // wave 0..3
  const int wr   = (w & 1) * 64;    // wave row offset
  const int wc   = (w >> 1) * 64;   // wave col offset
  const int l15  = lane & 15, l4 = lane >> 4;

  f32x4 acc[4][4];
#pragma unroll
  for (int m = 0; m < 4; ++m)
#pragma unroll
    for (int n = 0; n < 4; ++n) acc[m][n] = (f32x4){0.f, 0.f, 0.f, 0.f};

  const int srow = tid >> 1;   // staging row / local col, 0..127
  const int half = tid & 1;    // which 32-k half of the 64 K-step
  // B column geometry (fixed per thread)
  const int gn = fn * 128 + srow;
  const int bf_ = gn >> 1, bco = gn & 1;
  const float* wbase = ew + (((size_t)e * 256) * 256 + bf_) * 2;
  const int trow = tIdx[srow];

  for (int kk = 0; kk < J; kk += 64) {
    // ---- stage A: 8 bf16 per chunk, 4 chunks per thread
    {
      const float* src = x + (size_t)trow * J + kk + half * 32;
#pragma unroll
      for (int c = 0; c < 4; ++c) {
        float4 v0 = *(const float4*)(src + c * 8);
        float4 v1 = *(const float4*)(src + c * 8 + 4);
        union { unsigned short h[8]; bf16x8 v; } pk;
        pk.h[0] = f2bf(v0.x); pk.h[1] = f2bf(v0.y);
        pk.h[2] = f2bf(v0.z); pk.h[3] = f2bf(v0.w);
        pk.h[4] = f2bf(v1.x); pk.h[5] = f2bf(v1.y);
        pk.h[6] = f2bf(v1.z); pk.h[7] = f2bf(v1.w);
        int chunk = half * 4 + c;
        *(bf16x8*)(&As[srow * 64 + ((chunk ^ (srow & 7)) << 3)]) = pk.v;
      }
    }
    // ---- stage B: derive complex-expanded column
    {
#pragma unroll
      for (int c = 0; c < 4; ++c) {
        int chunk = half * 4 + c;
        int d0 = (kk >> 1) + chunk * 4;
        union { unsigned short h[8]; bf16x8 v; } pk;
#pragma unroll
        for (int dd = 0; dd < 4; ++dd) {
          float2 wv = *(const float2*)(wbase + (size_t)(d0 + dd) * 512);
          float b0 = bco ? wv.y : wv.x;    // k even (ci=0)
          float b1 = bco ? wv.x : -wv.y;   // k odd  (ci=1)
          pk.h[dd * 2]     = f2bf(b0);
          pk.h[dd * 2 + 1] = f2bf(b1);
        }
        *(bf16x8*)(&Bs[srow * 64 + ((chunk ^ (srow & 7)) << 3)]) = pk.v;
      }
    }
    __syncthreads();
    // ---- compute: 2 x 32-k slabs, 16 MFMAs each
#pragma unroll
    for (int kk2 = 0; kk2 < 2; ++kk2) {
      bf16x8 af[4], bfr[4];
#pragma unroll
      for (int m = 0; m < 4; ++m) {
        int r = wr + m * 16 + l15;
        int chunk = kk2 * 4 + l4;
        af[m] = *(const bf16x8*)(&As[r * 64 + ((chunk ^ (r & 7)) << 3)]);
      }
#pragma unroll
      for (int n = 0; n < 4; ++n) {
        int cl = wc + n * 16 + l15;
        int chunk = kk2 * 4 + l4;
        bfr[n] = *(const bf16x8*)(&Bs[cl * 64 + ((chunk ^ (cl & 7)) << 3)]);
      }
#pragma unroll
      for (int m = 0; m < 4; ++m)
#pragma unroll
        for (int n = 0; n < 4; ++n)
          acc[m][n] = __builtin_amdgcn_mfma_f32_16x16x32_bf16(
              af[m], bfr[n], acc[m][n], 0, 0, 0);
    }
    __syncthreads();
  }

  // ---- epilogue: scale by weight, scatter-add
#pragma unroll
  for (int m = 0; m < 4; ++m) {
#pragma unroll
    for (int q = 0; q < 4; ++q) {
      int rl = wr + m * 16 + l4 * 4 + q;  // C/D: row=(lane>>4)*4+reg
      int t = tIdx[rl];
      float wv = wRow[rl];
      float* dst = out + (size_t)t * J + fn * 128 + wc + l15;
#pragma unroll
      for (int n = 0; n < 4; ++n)
        atomicAdd(dst + n * 16, acc[m][n][q] * wv);
    }
  }
}

// ---------------------------------------------------------------------------
// K5: res = gelu(out / max(counts,1) + bias[f]), exact erf, in place, float4.
// ---------------------------------------------------------------------------
__global__ __launch_bounds__(256)
void k5_final(float* __restrict__ res, const float* __restrict__ cnt,
              const float* __restrict__ bias) {
  const int total4 = BT * J / 4;
  for (int i = blockIdx.x * blockDim.x + threadIdx.x; i < total4;
       i += gridDim.x * blockDim.x) {
    float4 v = reinterpret_cast<float4*>(res)[i];
    int base = i << 2;
    int t = base >> 9;
    int col = base & 511;
    float inv = 1.0f / fmaxf(cnt[t], 1.0f);
    int f0 = col >> 1;
    float b0 = bias[f0], b1 = bias[f0 + 1];
    float h0 = v.x * inv + b0;
    float h1 = v.y * inv + b0;
    float h2 = v.z * inv + b1;
    float h3 = v.w * inv + b1;
    const float is2 = 0.70710678118654752f;
    v.x = 0.5f * h0 * (1.0f + erff(h0 * is2));
    v.y = 0.5f * h1 * (1.0f + erff(h1 * is2));
    v.z = 0.5f * h2 * (1.0f + erff(h2 * is2));
    v.w = 0.5f * h3 * (1.0f + erff(h3 * is2));
    reinterpret_cast<float4*>(res)[i] = v;
  }
}

// ---------------------------------------------------------------------------
extern "C" void kernel_launch(void* const* d_in, const int* in_sizes, int n_in,
                              void* d_out, int out_size, void* d_ws,
                              size_t ws_size, hipStream_t stream) {
  const float* x    = (const float*)d_in[0];
  const float* gw   = (const float*)d_in[1];
  const float* ew   = (const float*)d_in[2];
  const float* bias = (const float*)d_in[3];

  float* out_f = (float*)d_out;
  float* res   = out_f;
  float* o_idx = out_f + OFF_IDX;
  float* o_scr = out_f + OFF_SCR;
  float* o_cnt = out_f + OFF_CNT;

  // scoresT (E x BT floats, 16 MiB) borrows the res region until top-k done.
  float* scoresT = res;

  hipMemsetAsync(o_cnt, 0, (size_t)BT * sizeof(float), stream);
  k1_scores<<<BT / 64, 256, 0, stream>>>(x, gw, scoresT);
  k2_topk<<<E, 1024, 0, stream>>>(scoresT, o_idx, o_scr, o_cnt);
  hipMemsetAsync(res, 0, (size_t)BT * J * sizeof(float), stream);
  k4_mfma<<<dim3(4, 16, E), 256, 0, stream>>>(x, ew, o_idx, o_scr, res);
  k5_final<<<8192, 256, 0, stream>>>(res, o_cnt, bias);
}

// Round 7
// 649.272 us; speedup vs baseline: 1.9396x; 1.0098x over previous
//
#include <hip/hip_runtime.h>
#include <math.h>

constexpr int BT = 65536;
constexpr int D  = 256;
constexpr int E  = 64;
constexpr int K  = 2048;
constexpr int J  = 512; // 2*D

// d_out layout (floats): res | topk_idx | topk_scores | counts
constexpr size_t OFF_IDX = (size_t)BT * D * 2;       // 33,554,432
constexpr size_t OFF_SCR = OFF_IDX + (size_t)E * K;  // +131,072
constexpr size_t OFF_CNT = OFF_SCR + (size_t)E * K;  // +131,072

// d_ws layout (bytes): xb bf16[BT][512] | Bmat bf16[E][512][512]
constexpr size_t WS_XB   = 0;
constexpr size_t WS_BM   = 67108864;          // 64 MiB
constexpr size_t WS_NEED = WS_BM + 33554432;  // 96 MiB total

typedef __attribute__((ext_vector_type(8))) short bf16x8;
typedef __attribute__((ext_vector_type(4))) float f32x4;

__device__ __forceinline__ unsigned short f2bf(float f) {
  unsigned u = __float_as_uint(f);
  u = (u + 0x7FFFu + ((u >> 16) & 1u)) >> 16;  // RTNE
  return (unsigned short)u;
}

// ---------------------------------------------------------------------------
// K1: scoresT[e][t] = fp32 dot as ONE sequential FMA chain j=0..511
// (bit-matches the np reference's sgemm scheme — DO NOT CHANGE).
// ---------------------------------------------------------------------------
__global__ __launch_bounds__(256)
void k1_scores(const float* __restrict__ x, const float* __restrict__ gw,
               float* __restrict__ scoresT) {
  __shared__ float xs[64][65];
  __shared__ float gs[64][68];
  const int t0 = blockIdx.x * 64;
  const int tid = threadIdx.x;
  const int tx = tid & 15;   // token sub-index
  const int ty = tid >> 4;   // expert group (4 experts per thread)
  float acc[4][4] = {};      // single chain j = 0..511

#define K1_STAGE(kk)                                                        \
  for (int i = tid; i < 4096; i += 256) {                                   \
    int r = i >> 6, c = i & 63;                                             \
    xs[r][c] = x[(size_t)(t0 + r) * J + (kk) * 64 + c];                     \
    gs[r][c] = gw[(size_t)((kk) * 64 + r) * E + c];                         \
  }                                                                         \
  __syncthreads();

#define K1_INNER(ACC)                                                       \
  _Pragma("unroll 16")                                                      \
  for (int j = 0; j < 64; ++j) {                                            \
    float xv[4], gv[4];                                                     \
    _Pragma("unroll") for (int a = 0; a < 4; ++a) xv[a] = xs[a*16+tx][j];   \
    _Pragma("unroll") for (int b = 0; b < 4; ++b) gv[b] = gs[j][ty*4+b];    \
    _Pragma("unroll") for (int a = 0; a < 4; ++a)                           \
      _Pragma("unroll") for (int b = 0; b < 4; ++b)                         \
        ACC[a][b] = fmaf(xv[a], gv[b], ACC[a][b]);                          \
  }                                                                         \
  __syncthreads();

  for (int kk = 0; kk < 8; ++kk) { K1_STAGE(kk) K1_INNER(acc) }

#pragma unroll
  for (int b = 0; b < 4; ++b) {
    int e = ty * 4 + b;
#pragma unroll
    for (int a = 0; a < 4; ++a)
      scoresT[(size_t)e * BT + t0 + a * 16 + tx] = acc[a][b];
  }
}

// ---------------------------------------------------------------------------
// K2: per-expert top-K on fp32 scores (descending; ties -> lower index,
// stable). Radix-select + bitonic sort of (score_u32 << 32 | ~idx).
// Verified passing — DO NOT CHANGE.
// ---------------------------------------------------------------------------
__device__ __forceinline__ unsigned fkey(float s) {
  unsigned u = __float_as_uint(s);
  return (u & 0x80000000u) ? ~u : (u | 0x80000000u);
}

__global__ __launch_bounds__(1024)
void k2_topk(const float* __restrict__ scoresT, float* __restrict__ o_idx,
             float* __restrict__ o_scr, float* __restrict__ o_cnt) {
  const int e = blockIdx.x;
  const float* row = scoresT + (size_t)e * BT;
  __shared__ unsigned hist[16][256];  // per-wave sub-histograms
  __shared__ unsigned sh_need, sh_prefix;
  __shared__ int sh_n;
  __shared__ unsigned long long keys[4096];
  const int tid = threadIdx.x;
  const int wv = tid >> 6;

  unsigned mask = 0u, prefix = 0u, need = (unsigned)K;
  for (int pass = 0; pass < 4; ++pass) {
    const int shift = 24 - 8 * pass;
    for (int i = tid; i < 16 * 256; i += 1024) ((unsigned*)hist)[i] = 0u;
    __syncthreads();
    for (int i = tid; i < BT; i += 1024) {
      unsigned u = fkey(row[i]);
      if ((u & mask) == prefix) atomicAdd(&hist[wv][(u >> shift) & 0xFFu], 1u);
    }
    __syncthreads();
    if (tid < 256) {
      unsigned s = 0;
#pragma unroll
      for (int w = 0; w < 16; ++w) s += hist[w][tid];
      hist[0][tid] = s;
    }
    __syncthreads();
    if (tid == 0) {
      unsigned cum = 0u; int b = 0;
      for (int v = 255; v >= 0; --v) {
        unsigned h = hist[0][v];
        if (cum + h >= need) { b = v; break; }
        cum += h;
      }
      sh_need = need - cum;
      sh_prefix = prefix | ((unsigned)b << shift);
    }
    __syncthreads();
    need = sh_need;
    prefix = sh_prefix;
    mask |= (0xFFu << shift);
    __syncthreads();
  }
  const unsigned u_thr = prefix;  // exact K-th key value
  if (tid == 0) sh_n = 0;
  __syncthreads();
  for (int i = tid; i < BT; i += 1024) {
    unsigned u = fkey(row[i]);
    if (u >= u_thr) {
      int pos = atomicAdd(&sh_n, 1);
      if (pos < 4096)
        keys[pos] = ((unsigned long long)u << 32) | (unsigned)(~(unsigned)i);
    }
  }
  __syncthreads();
  int n = sh_n; if (n > 4096) n = 4096;
  for (int i = n + tid; i < 4096; i += 1024) keys[i] = 0ull;
  __syncthreads();
  // bitonic sort, descending: (score desc, then idx asc via ~idx desc)
  for (int kk = 2; kk <= 4096; kk <<= 1) {
    for (int j = kk >> 1; j > 0; j >>= 1) {
      for (int i = tid; i < 4096; i += 1024) {
        int ij = i ^ j;
        if (ij > i) {
          bool up = ((i & kk) == 0);
          unsigned long long a = keys[i], b = keys[ij];
          if ((a < b) == up) { keys[i] = b; keys[ij] = a; }
        }
      }
      __syncthreads();
    }
  }
  for (int r = tid; r < K; r += 1024) {
    unsigned long long kv = keys[r];
    unsigned u = (unsigned)(kv >> 32);
    unsigned idx = ~((unsigned)kv);
    float s = __uint_as_float((u & 0x80000000u) ? (u ^ 0x80000000u) : ~u);
    o_idx[(size_t)e * K + r] = (float)idx;
    o_scr[(size_t)e * K + r] = s;
    atomicAdd(&o_cnt[idx], 1.0f);
  }
}

// ---------------------------------------------------------------------------
// K3a: xb[t][k] = bf16(x[t][k]), 8 elements/thread.
// ---------------------------------------------------------------------------
__global__ __launch_bounds__(256)
void k3a_xbf(const float* __restrict__ x, unsigned short* __restrict__ xb) {
  int i = blockIdx.x * 256 + threadIdx.x;  // group of 8 floats
  float4 v0 = ((const float4*)x)[i * 2];
  float4 v1 = ((const float4*)x)[i * 2 + 1];
  union { unsigned short h[8]; bf16x8 v; } pk;
  pk.h[0] = f2bf(v0.x); pk.h[1] = f2bf(v0.y);
  pk.h[2] = f2bf(v0.z); pk.h[3] = f2bf(v0.w);
  pk.h[4] = f2bf(v1.x); pk.h[5] = f2bf(v1.y);
  pk.h[6] = f2bf(v1.z); pk.h[7] = f2bf(v1.w);
  ((bf16x8*)xb)[i] = pk.v;
}

// ---------------------------------------------------------------------------
// K3b: Bmat[e][n=2f+co][k=2d+ci] = bf16( ew[e][d][f][ci^co] * sign ),
// sign = -1 iff (ci==1 && co==0). 8 k-values (4 d's) per thread.
// ---------------------------------------------------------------------------
__global__ __launch_bounds__(256)
void k3b_bmat(const float* __restrict__ ew, unsigned short* __restrict__ bm) {
  int id = blockIdx.x * 256 + threadIdx.x;  // one bf16x8 output
  int sub = id & 63;       // which k-octet
  int ng  = id >> 6;       // e*512 + n
  int e   = ng >> 9;
  int n   = ng & 511;
  int f   = n >> 1, co = n & 1;
  int d0  = sub * 4;
  const float* wb = ew + (((size_t)e * 256) * 256 + f) * 2;
  union { unsigned short h[8]; bf16x8 v; } pk;
#pragma unroll
  for (int dd = 0; dd < 4; ++dd) {
    float2 wv = *(const float2*)(wb + (size_t)(d0 + dd) * 512);
    float b0 = co ? wv.y : wv.x;    // ci=0
    float b1 = co ? wv.x : -wv.y;   // ci=1
    pk.h[dd * 2]     = f2bf(b0);
    pk.h[dd * 2 + 1] = f2bf(b1);
  }
  ((bf16x8*)bm)[id] = pk.v;
}

// ---------------------------------------------------------------------------
// K4b (MFMA bf16, global_load_lds staging): per-expert GEMM M=2048,N=512,K=512
// on precomputed bf16 operands. 128x128 tile, 4 waves, BK=64.
// LDS linear dest + pre-swizzled global source chunk (gch = slot ^ row&7);
// frag reads use the same involution -> identical data layout & numerics as
// the round-6 kernel (bit-identical result).
// ---------------------------------------------------------------------------
__device__ __forceinline__ void gl16(const void* g, void* l) {
  __builtin_amdgcn_global_load_lds(
      (const __attribute__((address_space(1))) unsigned int*)g,
      (__attribute__((address_space(3))) unsigned int*)l, 16, 0, 0);
}

__global__ __launch_bounds__(256)
void k4b_mfma(const unsigned short* __restrict__ xb,
              const unsigned short* __restrict__ bm,
              const float* __restrict__ o_idx, const float* __restrict__ o_scr,
              float* __restrict__ out) {
  const int e  = blockIdx.z;
  const int km = blockIdx.y;  // M tile (0..15)
  const int fn = blockIdx.x;  // N tile (0..3)
  __shared__ __align__(16) unsigned short As[128 * 64];
  __shared__ __align__(16) unsigned short Bs[128 * 64];
  __shared__ int   tIdx[128];
  __shared__ float wRow[128];
  const int tid = threadIdx.x;
  if (tid < 128) {
    size_t gi = (size_t)e * K + km * 128 + tid;
    tIdx[tid] = (int)o_idx[gi];
    wRow[tid] = o_scr[gi];
  }
  __syncthreads();

  const int lane = tid & 63;
  const int w    = tid >> 6;
  const int wr   = (w & 1) * 64;
  const int wc   = (w >> 1) * 64;
  const int l15  = lane & 15, l4 = lane >> 4;
  const int ls   = lane & 7, lr = lane >> 3;
  const int gch  = ls ^ lr;  // pre-swizzled source chunk (row&7 == lr)

  // per-lane global source bases (bytes) and LDS dests for 4 row-octets
  const char* aSrc[4];
  const char* bSrc[4];
  unsigned short* aDst[4];
  unsigned short* bDst[4];
#pragma unroll
  for (int i = 0; i < 4; ++i) {
    int r = w * 32 + i * 8 + lr;
    aSrc[i] = (const char*)xb + (size_t)tIdx[r] * 1024 + gch * 16;
    bSrc[i] = (const char*)bm + ((size_t)e * 512 + fn * 128 + r) * 1024 +
              gch * 16;
    aDst[i] = As + (w * 32 + i * 8) * 64 + lane * 8;
    bDst[i] = Bs + (w * 32 + i * 8) * 64 + lane * 8;
  }

  f32x4 acc[4][4];
#pragma unroll
  for (int m = 0; m < 4; ++m)
#pragma unroll
    for (int n = 0; n < 4; ++n) acc[m][n] = (f32x4){0.f, 0.f, 0.f, 0.f};

  for (int kk = 0; kk < J; kk += 64) {
#pragma unroll
    for (int i = 0; i < 4; ++i) {
      gl16(aSrc[i] + kk * 2, aDst[i]);
      gl16(bSrc[i] + kk * 2, bDst[i]);
    }
    __syncthreads();
#pragma unroll
    for (int kk2 = 0; kk2 < 2; ++kk2) {
      bf16x8 af[4], bfr[4];
#pragma unroll
      for (int m = 0; m < 4; ++m) {
        int r = wr + m * 16 + l15;
        int s = (kk2 * 4 + l4) ^ (r & 7);
        af[m] = *(const bf16x8*)(&As[r * 64 + s * 8]);
      }
#pragma unroll
      for (int n = 0; n < 4; ++n) {
        int cl = wc + n * 16 + l15;
        int s = (kk2 * 4 + l4) ^ (cl & 7);
        bfr[n] = *(const bf16x8*)(&Bs[cl * 64 + s * 8]);
      }
#pragma unroll
      for (int m = 0; m < 4; ++m)
#pragma unroll
        for (int n = 0; n < 4; ++n)
          acc[m][n] = __builtin_amdgcn_mfma_f32_16x16x32_bf16(
              af[m], bfr[n], acc[m][n], 0, 0, 0);
    }
    __syncthreads();
  }

#pragma unroll
  for (int m = 0; m < 4; ++m) {
#pragma unroll
    for (int q = 0; q < 4; ++q) {
      int rl = wr + m * 16 + l4 * 4 + q;
      int t = tIdx[rl];
      float wv = wRow[rl];
      float* dst = out + (size_t)t * J + fn * 128 + wc + l15;
#pragma unroll
      for (int n = 0; n < 4; ++n)
        atomicAdd(dst + n * 16, acc[m][n][q] * wv);
    }
  }
}

// ---------------------------------------------------------------------------
// K4 (fallback, no workspace): round-6 verified kernel.
// ---------------------------------------------------------------------------
__global__ __launch_bounds__(256)
void k4_mfma(const float* __restrict__ x, const float* __restrict__ ew,
             const float* __restrict__ o_idx, const float* __restrict__ o_scr,
             float* __restrict__ out) {
  const int e  = blockIdx.z;
  const int km = blockIdx.y;
  const int fn = blockIdx.x;
  __shared__ __align__(16) unsigned short As[128 * 64];
  __shared__ __align__(16) unsigned short Bs[128 * 64];
  __shared__ int   tIdx[128];
  __shared__ float wRow[128];
  const int tid = threadIdx.x;
  if (tid < 128) {
    size_t gi = (size_t)e * K + km * 128 + tid;
    tIdx[tid] = (int)o_idx[gi];
    wRow[tid] = o_scr[gi];
  }
  __syncthreads();

  const int lane = tid & 63;
  const int w    = tid >> 6;
  const int wr   = (w & 1) * 64;
  const int wc   = (w >> 1) * 64;
  const int l15  = lane & 15, l4 = lane >> 4;

  f32x4 acc[4][4];
#pragma unroll
  for (int m = 0; m < 4; ++m)
#pragma unroll
    for (int n = 0; n < 4; ++n) acc[m][n] = (f32x4){0.f, 0.f, 0.f, 0.f};

  const int srow = tid >> 1;
  const int half = tid & 1;
  const int gn = fn * 128 + srow;
  const int bf_ = gn >> 1, bco = gn & 1;
  const float* wbase = ew + (((size_t)e * 256) * 256 + bf_) * 2;
  const int trow = tIdx[srow];

  for (int kk = 0; kk < J; kk += 64) {
    {
      const float* src = x + (size_t)trow * J + kk + half * 32;
#pragma unroll
      for (int c = 0; c < 4; ++c) {
        float4 v0 = *(const float4*)(src + c * 8);
        float4 v1 = *(const float4*)(src + c * 8 + 4);
        union { unsigned short h[8]; bf16x8 v; } pk;
        pk.h[0] = f2bf(v0.x); pk.h[1] = f2bf(v0.y);
        pk.h[2] = f2bf(v0.z); pk.h[3] = f2bf(v0.w);
        pk.h[4] = f2bf(v1.x); pk.h[5] = f2bf(v1.y);
        pk.h[6] = f2bf(v1.z); pk.h[7] = f2bf(v1.w);
        int chunk = half * 4 + c;
        *(bf16x8*)(&As[srow * 64 + ((chunk ^ (srow & 7)) << 3)]) = pk.v;
      }
    }
    {
#pragma unroll
      for (int c = 0; c < 4; ++c) {
        int chunk = half * 4 + c;
        int d0 = (kk >> 1) + chunk * 4;
        union { unsigned short h[8]; bf16x8 v; } pk;
#pragma unroll
        for (int dd = 0; dd < 4; ++dd) {
          float2 wv = *(const float2*)(wbase + (size_t)(d0 + dd) * 512);
          float b0 = bco ? wv.y : wv.x;
          float b1 = bco ? wv.x : -wv.y;
          pk.h[dd * 2]     = f2bf(b0);
          pk.h[dd * 2 + 1] = f2bf(b1);
        }
        *(bf16x8*)(&Bs[srow * 64 + ((chunk ^ (srow & 7)) << 3)]) = pk.v;
      }
    }
    __syncthreads();
#pragma unroll
    for (int kk2 = 0; kk2 < 2; ++kk2) {
      bf16x8 af[4], bfr[4];
#pragma unroll
      for (int m = 0; m < 4; ++m) {
        int r = wr + m * 16 + l15;
        int chunk = kk2 * 4 + l4;
        af[m] = *(const bf16x8*)(&As[r * 64 + ((chunk ^ (r & 7)) << 3)]);
      }
#pragma unroll
      for (int n = 0; n < 4; ++n) {
        int cl = wc + n * 16 + l15;
        int chunk = kk2 * 4 + l4;
        bfr[n] = *(const bf16x8*)(&Bs[cl * 64 + ((chunk ^ (cl & 7)) << 3)]);
      }
#pragma unroll
      for (int m = 0; m < 4; ++m)
#pragma unroll
        for (int n = 0; n < 4; ++n)
          acc[m][n] = __builtin_amdgcn_mfma_f32_16x16x32_bf16(
              af[m], bfr[n], acc[m][n], 0, 0, 0);
    }
    __syncthreads();
  }

#pragma unroll
  for (int m = 0; m < 4; ++m) {
#pragma unroll
    for (int q = 0; q < 4; ++q) {
      int rl = wr + m * 16 + l4 * 4 + q;
      int t = tIdx[rl];
      float wv = wRow[rl];
      float* dst = out + (size_t)t * J + fn * 128 + wc + l15;
#pragma unroll
      for (int n = 0; n < 4; ++n)
        atomicAdd(dst + n * 16, acc[m][n][q] * wv);
    }
  }
}

// ---------------------------------------------------------------------------
// K5: res = gelu(out / max(counts,1) + bias[f]), exact erf, in place, float4.
// ---------------------------------------------------------------------------
__global__ __launch_bounds__(256)
void k5_final(float* __restrict__ res, const float* __restrict__ cnt,
              const float* __restrict__ bias) {
  const int total4 = BT * J / 4;
  for (int i = blockIdx.x * blockDim.x + threadIdx.x; i < total4;
       i += gridDim.x * blockDim.x) {
    float4 v = reinterpret_cast<float4*>(res)[i];
    int base = i << 2;
    int t = base >> 9;
    int col = base & 511;
    float inv = 1.0f / fmaxf(cnt[t], 1.0f);
    int f0 = col >> 1;
    float b0 = bias[f0], b1 = bias[f0 + 1];
    float h0 = v.x * inv + b0;
    float h1 = v.y * inv + b0;
    float h2 = v.z * inv + b1;
    float h3 = v.w * inv + b1;
    const float is2 = 0.70710678118654752f;
    v.x = 0.5f * h0 * (1.0f + erff(h0 * is2));
    v.y = 0.5f * h1 * (1.0f + erff(h1 * is2));
    v.z = 0.5f * h2 * (1.0f + erff(h2 * is2));
    v.w = 0.5f * h3 * (1.0f + erff(h3 * is2));
    reinterpret_cast<float4*>(res)[i] = v;
  }
}

// ---------------------------------------------------------------------------
extern "C" void kernel_launch(void* const* d_in, const int* in_sizes, int n_in,
                              void* d_out, int out_size, void* d_ws,
                              size_t ws_size, hipStream_t stream) {
  const float* x    = (const float*)d_in[0];
  const float* gw   = (const float*)d_in[1];
  const float* ew   = (const float*)d_in[2];
  const float* bias = (const float*)d_in[3];

  float* out_f = (float*)d_out;
  float* res   = out_f;
  float* o_idx = out_f + OFF_IDX;
  float* o_scr = out_f + OFF_SCR;
  float* o_cnt = out_f + OFF_CNT;

  // scoresT (E x BT floats, 16 MiB) borrows the res region until top-k done.
  float* scoresT = res;

  const bool useWs = (ws_size >= WS_NEED);
  unsigned short* xb = (unsigned short*)((char*)d_ws + WS_XB);
  unsigned short* bm = (unsigned short*)((char*)d_ws + WS_BM);

  if (useWs) {
    k3a_xbf<<<16384, 256, 0, stream>>>(x, xb);
    k3b_bmat<<<8192, 256, 0, stream>>>(ew, bm);
  }
  hipMemsetAsync(o_cnt, 0, (size_t)BT * sizeof(float), stream);
  k1_scores<<<BT / 64, 256, 0, stream>>>(x, gw, scoresT);
  k2_topk<<<E, 1024, 0, stream>>>(scoresT, o_idx, o_scr, o_cnt);
  hipMemsetAsync(res, 0, (size_t)BT * J * sizeof(float), stream);
  if (useWs)
    k4b_mfma<<<dim3(4, 16, E), 256, 0, stream>>>(xb, bm, o_idx, o_scr, res);
  else
    k4_mfma<<<dim3(4, 16, E), 256, 0, stream>>>(x, ew, o_idx, o_scr, res);
  k5_final<<<8192, 256, 0, stream>>>(res, o_cnt, bias);
}

// Round 8
// 533.766 us; speedup vs baseline: 2.3593x; 1.2164x over previous
//
#include <hip/hip_runtime.h>
#include <hip/hip_fp16.h>
#include <math.h>

constexpr int BT = 65536;
constexpr int D  = 256;
constexpr int E  = 64;
constexpr int K  = 2048;
constexpr int J  = 512; // 2*D

// d_out layout (floats): res | topk_idx | topk_scores | counts
constexpr size_t OFF_IDX = (size_t)BT * D * 2;       // 33,554,432
constexpr size_t OFF_SCR = OFF_IDX + (size_t)E * K;  // +131,072
constexpr size_t OFF_CNT = OFF_SCR + (size_t)E * K;  // +131,072

// d_ws layout (bytes):
//   xb   bf16[BT][512]        @ 0          (64 MiB)
//   bm   bf16[E][512][512]    @ 64 MiB     (32 MiB)
//   yD   fp16[E*K][512]       @ 96 MiB     (128 MiB)   [tier-1 only]
//   cur  int[BT]              @ 224 MiB    (256 KiB)   [tier-1 only]
//   slot int[BT][32]          @ 224.25 MiB (8 MiB)     [tier-1 only]
constexpr size_t WS_XB    = 0;
constexpr size_t WS_BM    = 67108864;
constexpr size_t WS_YD    = 100663296;
constexpr size_t WS_CUR   = 234881024;
constexpr size_t WS_SLOT  = 235143168;
constexpr size_t WS_NEED1 = 243531776;              // tier-1: full path
constexpr size_t WS_NEED2 = 100663296;              // tier-2: round-7 path
constexpr int    SLOT_PAD = 32;

typedef __attribute__((ext_vector_type(8))) short bf16x8;
typedef __attribute__((ext_vector_type(4))) float f32x4;

__device__ __forceinline__ unsigned short f2bf(float f) {
  unsigned u = __float_as_uint(f);
  u = (u + 0x7FFFu + ((u >> 16) & 1u)) >> 16;  // RTNE
  return (unsigned short)u;
}

__device__ __forceinline__ void gl16(const void* g, void* l) {
  __builtin_amdgcn_global_load_lds(
      (const __attribute__((address_space(1))) unsigned int*)g,
      (__attribute__((address_space(3))) unsigned int*)l, 16, 0, 0);
}

// ---------------------------------------------------------------------------
// K1: scoresT[e][t] = fp32 dot as ONE sequential FMA chain j=0..511
// (bit-matches the np reference's sgemm scheme — DO NOT CHANGE).
// ---------------------------------------------------------------------------
__global__ __launch_bounds__(256)
void k1_scores(const float* __restrict__ x, const float* __restrict__ gw,
               float* __restrict__ scoresT) {
  __shared__ float xs[64][65];
  __shared__ float gs[64][68];
  const int t0 = blockIdx.x * 64;
  const int tid = threadIdx.x;
  const int tx = tid & 15;
  const int ty = tid >> 4;
  float acc[4][4] = {};

#define K1_STAGE(kk)                                                        \
  for (int i = tid; i < 4096; i += 256) {                                   \
    int r = i >> 6, c = i & 63;                                             \
    xs[r][c] = x[(size_t)(t0 + r) * J + (kk) * 64 + c];                     \
    gs[r][c] = gw[(size_t)((kk) * 64 + r) * E + c];                         \
  }                                                                         \
  __syncthreads();

#define K1_INNER(ACC)                                                       \
  _Pragma("unroll 16")                                                      \
  for (int j = 0; j < 64; ++j) {                                            \
    float xv[4], gv[4];                                                     \
    _Pragma("unroll") for (int a = 0; a < 4; ++a) xv[a] = xs[a*16+tx][j];   \
    _Pragma("unroll") for (int b = 0; b < 4; ++b) gv[b] = gs[j][ty*4+b];    \
    _Pragma("unroll") for (int a = 0; a < 4; ++a)                           \
      _Pragma("unroll") for (int b = 0; b < 4; ++b)                         \
        ACC[a][b] = fmaf(xv[a], gv[b], ACC[a][b]);                          \
  }                                                                         \
  __syncthreads();

  for (int kk = 0; kk < 8; ++kk) { K1_STAGE(kk) K1_INNER(acc) }

#pragma unroll
  for (int b = 0; b < 4; ++b) {
    int e = ty * 4 + b;
#pragma unroll
    for (int a = 0; a < 4; ++a)
      scoresT[(size_t)e * BT + t0 + a * 16 + tx] = acc[a][b];
  }
}

// ---------------------------------------------------------------------------
// K2: per-expert top-K on fp32 scores (descending; ties -> lower index,
// stable). Radix-select + bitonic sort of (score_u32 << 32 | ~idx).
// Verified passing — selection/sort unchanged. Optionally appends the
// inverse token->slot map (tier-1).
// ---------------------------------------------------------------------------
__device__ __forceinline__ unsigned fkey(float s) {
  unsigned u = __float_as_uint(s);
  return (u & 0x80000000u) ? ~u : (u | 0x80000000u);
}

__global__ __launch_bounds__(1024)
void k2_topk(const float* __restrict__ scoresT, float* __restrict__ o_idx,
             float* __restrict__ o_scr, float* __restrict__ o_cnt,
             int* __restrict__ cur, int* __restrict__ slots) {
  const int e = blockIdx.x;
  const float* row = scoresT + (size_t)e * BT;
  __shared__ unsigned hist[16][256];
  __shared__ unsigned sh_need, sh_prefix;
  __shared__ int sh_n;
  __shared__ unsigned long long keys[4096];
  const int tid = threadIdx.x;
  const int wv = tid >> 6;

  unsigned mask = 0u, prefix = 0u, need = (unsigned)K;
  for (int pass = 0; pass < 4; ++pass) {
    const int shift = 24 - 8 * pass;
    for (int i = tid; i < 16 * 256; i += 1024) ((unsigned*)hist)[i] = 0u;
    __syncthreads();
    for (int i = tid; i < BT; i += 1024) {
      unsigned u = fkey(row[i]);
      if ((u & mask) == prefix) atomicAdd(&hist[wv][(u >> shift) & 0xFFu], 1u);
    }
    __syncthreads();
    if (tid < 256) {
      unsigned s = 0;
#pragma unroll
      for (int w = 0; w < 16; ++w) s += hist[w][tid];
      hist[0][tid] = s;
    }
    __syncthreads();
    if (tid == 0) {
      unsigned cum = 0u; int b = 0;
      for (int v = 255; v >= 0; --v) {
        unsigned h = hist[0][v];
        if (cum + h >= need) { b = v; break; }
        cum += h;
      }
      sh_need = need - cum;
      sh_prefix = prefix | ((unsigned)b << shift);
    }
    __syncthreads();
    need = sh_need;
    prefix = sh_prefix;
    mask |= (0xFFu << shift);
    __syncthreads();
  }
  const unsigned u_thr = prefix;
  if (tid == 0) sh_n = 0;
  __syncthreads();
  for (int i = tid; i < BT; i += 1024) {
    unsigned u = fkey(row[i]);
    if (u >= u_thr) {
      int pos = atomicAdd(&sh_n, 1);
      if (pos < 4096)
        keys[pos] = ((unsigned long long)u << 32) | (unsigned)(~(unsigned)i);
    }
  }
  __syncthreads();
  int n = sh_n; if (n > 4096) n = 4096;
  for (int i = n + tid; i < 4096; i += 1024) keys[i] = 0ull;
  __syncthreads();
  for (int kk = 2; kk <= 4096; kk <<= 1) {
    for (int j = kk >> 1; j > 0; j >>= 1) {
      for (int i = tid; i < 4096; i += 1024) {
        int ij = i ^ j;
        if (ij > i) {
          bool up = ((i & kk) == 0);
          unsigned long long a = keys[i], b = keys[ij];
          if ((a < b) == up) { keys[i] = b; keys[ij] = a; }
        }
      }
      __syncthreads();
    }
  }
  for (int r = tid; r < K; r += 1024) {
    unsigned long long kv = keys[r];
    unsigned u = (unsigned)(kv >> 32);
    unsigned idx = ~((unsigned)kv);
    float s = __uint_as_float((u & 0x80000000u) ? (u ^ 0x80000000u) : ~u);
    o_idx[(size_t)e * K + r] = (float)idx;
    o_scr[(size_t)e * K + r] = s;
    atomicAdd(&o_cnt[idx], 1.0f);
    if (slots) {
      int pos = atomicAdd(&cur[idx], 1);
      if (pos < SLOT_PAD) slots[(size_t)idx * SLOT_PAD + pos] = e * K + r;
    }
  }
}

// ---------------------------------------------------------------------------
// K3a: xb[t][k] = bf16(x[t][k]), 8 elements/thread.
// ---------------------------------------------------------------------------
__global__ __launch_bounds__(256)
void k3a_xbf(const float* __restrict__ x, unsigned short* __restrict__ xb) {
  int i = blockIdx.x * 256 + threadIdx.x;
  float4 v0 = ((const float4*)x)[i * 2];
  float4 v1 = ((const float4*)x)[i * 2 + 1];
  union { unsigned short h[8]; bf16x8 v; } pk;
  pk.h[0] = f2bf(v0.x); pk.h[1] = f2bf(v0.y);
  pk.h[2] = f2bf(v0.z); pk.h[3] = f2bf(v0.w);
  pk.h[4] = f2bf(v1.x); pk.h[5] = f2bf(v1.y);
  pk.h[6] = f2bf(v1.z); pk.h[7] = f2bf(v1.w);
  ((bf16x8*)xb)[i] = pk.v;
}

// ---------------------------------------------------------------------------
// K3b: Bmat[e][n=2f+co][k=2d+ci] = bf16( ew[e][d][f][ci^co] * sign ).
// ---------------------------------------------------------------------------
__global__ __launch_bounds__(256)
void k3b_bmat(const float* __restrict__ ew, unsigned short* __restrict__ bm) {
  int id = blockIdx.x * 256 + threadIdx.x;
  int sub = id & 63;
  int ng  = id >> 6;
  int e   = ng >> 9;
  int n   = ng & 511;
  int f   = n >> 1, co = n & 1;
  int d0  = sub * 4;
  const float* wb = ew + (((size_t)e * 256) * 256 + f) * 2;
  union { unsigned short h[8]; bf16x8 v; } pk;
#pragma unroll
  for (int dd = 0; dd < 4; ++dd) {
    float2 wv = *(const float2*)(wb + (size_t)(d0 + dd) * 512);
    float b0 = co ? wv.y : wv.x;
    float b1 = co ? wv.x : -wv.y;
    pk.h[dd * 2]     = f2bf(b0);
    pk.h[dd * 2 + 1] = f2bf(b1);
  }
  ((bf16x8*)bm)[id] = pk.v;
}

// ---------------------------------------------------------------------------
// K4c (tier-1): MFMA bf16 GEMM, dense fp16 output (NO atomics).
// 128x128 tile, BK=64, double-buffered LDS (2-phase: barrier -> stage next
// -> compute current, so next-tile gl_lds flies under MFMA).
// Block mapping: bid = xcd + 8*(fn + 4*km + 64*e_hi), e = xcd + 8*e_hi
// -> all blocks of one expert on one XCD (B-panel L2 locality); fn-blocks
// sharing gathered A rows adjacent in sequence.
// Epilogue: acc*w -> fp16 via LDS repack -> coalesced yD stores.
// ---------------------------------------------------------------------------
__global__ __launch_bounds__(256)
void k4c_mfma(const unsigned short* __restrict__ xb,
              const unsigned short* __restrict__ bm,
              const float* __restrict__ o_idx, const float* __restrict__ o_scr,
              unsigned short* __restrict__ yD) {
  const int bid = blockIdx.x;
  const int xcd = bid & 7;
  const int s   = bid >> 3;
  const int fn  = s & 3;
  const int km  = (s >> 2) & 15;
  const int e   = xcd + ((s >> 6) << 3);

  __shared__ __align__(16) unsigned short As[2 * 128 * 64];
  __shared__ __align__(16) unsigned short Bs[2 * 128 * 64];
  __shared__ int   tIdx[128];
  __shared__ float wRow[128];
  const int tid = threadIdx.x;
  if (tid < 128) {
    size_t gi = (size_t)e * K + km * 128 + tid;
    tIdx[tid] = (int)o_idx[gi];
    wRow[tid] = o_scr[gi];
  }
  __syncthreads();

  const int lane = tid & 63;
  const int w    = tid >> 6;
  const int wr   = (w & 1) * 64;
  const int wc   = (w >> 1) * 64;
  const int l15  = lane & 15, l4 = lane >> 4;
  const int ls   = lane & 7, lr = lane >> 3;
  const int gch  = ls ^ lr;  // pre-swizzled source chunk

  const char* aSrc[4];
  const char* bSrc[4];
  int dstOff[4];
#pragma unroll
  for (int i = 0; i < 4; ++i) {
    int r = w * 32 + i * 8 + lr;
    aSrc[i] = (const char*)xb + (size_t)tIdx[r] * 1024 + gch * 16;
    bSrc[i] = (const char*)bm + ((size_t)e * 512 + fn * 128 + r) * 1024 +
              gch * 16;
    dstOff[i] = (w * 32 + i * 8) * 64 + lane * 8;
  }

  f32x4 acc[4][4];
#pragma unroll
  for (int m = 0; m < 4; ++m)
#pragma unroll
    for (int n = 0; n < 4; ++n) acc[m][n] = (f32x4){0.f, 0.f, 0.f, 0.f};

  // prologue: stage K-step 0 into buffer 0
#pragma unroll
  for (int i = 0; i < 4; ++i) {
    gl16(aSrc[i], As + dstOff[i]);
    gl16(bSrc[i], Bs + dstOff[i]);
  }

#pragma unroll
  for (int t = 0; t < 8; ++t) {
    const int cur = t & 1;
    __syncthreads();  // drains vmcnt -> buffer `cur` ready
    if (t < 7) {      // stage next tile into cur^1 while computing cur
      const int nxt = (cur ^ 1) * 8192;
#pragma unroll
      for (int i = 0; i < 4; ++i) {
        gl16(aSrc[i] + (t + 1) * 128, As + nxt + dstOff[i]);
        gl16(bSrc[i] + (t + 1) * 128, Bs + nxt + dstOff[i]);
      }
    }
    const unsigned short* Ab = As + cur * 8192;
    const unsigned short* Bb = Bs + cur * 8192;
#pragma unroll
    for (int kk2 = 0; kk2 < 2; ++kk2) {
      bf16x8 af[4], bfr[4];
#pragma unroll
      for (int m = 0; m < 4; ++m) {
        int r = wr + m * 16 + l15;
        int sw = (kk2 * 4 + l4) ^ (r & 7);
        af[m] = *(const bf16x8*)(&Ab[r * 64 + sw * 8]);
      }
#pragma unroll
      for (int n = 0; n < 4; ++n) {
        int cl = wc + n * 16 + l15;
        int sw = (kk2 * 4 + l4) ^ (cl & 7);
        bfr[n] = *(const bf16x8*)(&Bb[cl * 64 + sw * 8]);
      }
#pragma unroll
      for (int m = 0; m < 4; ++m)
#pragma unroll
        for (int n = 0; n < 4; ++n)
          acc[m][n] = __builtin_amdgcn_mfma_f32_16x16x32_bf16(
              af[m], bfr[n], acc[m][n], 0, 0, 0);
    }
  }

  // epilogue: weight, fp16-pack via LDS repack (reuse As: 128x128 halfs)
  __syncthreads();
  unsigned short* Pk = As;  // 16384 ushorts
#pragma unroll
  for (int m = 0; m < 4; ++m) {
#pragma unroll
    for (int q = 0; q < 4; ++q) {
      int row = wr + m * 16 + l4 * 4 + q;
      float wv = wRow[row];
#pragma unroll
      for (int n = 0; n < 4; ++n) {
        int col = wc + n * 16 + l15;
        Pk[row * 128 + col] =
            __half_as_ushort(__float2half(acc[m][n][q] * wv));
      }
    }
  }
  __syncthreads();
  const size_t rowBase = (size_t)e * K + km * 128;
#pragma unroll
  for (int i = 0; i < 8; ++i) {
    int c2 = tid + 256 * i;       // 2048 chunks of 16B
    int row = c2 >> 4, ch = c2 & 15;
    uint4 v = *(const uint4*)(&Pk[row * 128 + ch * 8]);
    *(uint4*)(yD + (rowBase + row) * 512 + fn * 128 + ch * 8) = v;
  }
}

// ---------------------------------------------------------------------------
// K5g (tier-1): per-token gather-finalize. One wave per token:
// res[t] = gelu( sum_slots(yD[slot]) / max(cnt,1) + bias ), exact erf.
// ---------------------------------------------------------------------------
__global__ __launch_bounds__(256)
void k5g(const unsigned short* __restrict__ yD, const int* __restrict__ cur,
         const int* __restrict__ slots, const float* __restrict__ bias,
         float* __restrict__ res) {
  const int t    = blockIdx.x * 4 + (threadIdx.x >> 6);
  const int lane = threadIdx.x & 63;
  const int nc   = cur[t];
  const int ncc  = nc < SLOT_PAD ? nc : SLOT_PAD;
  float acc[8] = {};
  const int* sl = slots + (size_t)t * SLOT_PAD;
  for (int c = 0; c < ncc; ++c) {
    int slot = sl[c];
    union { uint4 v; unsigned short h[8]; } U;
    U.v = *(const uint4*)(yD + (size_t)slot * 512 + lane * 8);
#pragma unroll
    for (int j = 0; j < 8; ++j)
      acc[j] += __half2float(__ushort_as_half(U.h[j]));
  }
  const float inv = 1.0f / fmaxf((float)nc, 1.0f);
  float4 b4 = *(const float4*)(bias + lane * 4);
  const float* bp = (const float*)&b4;
  const float is2 = 0.70710678118654752f;
  float r8[8];
#pragma unroll
  for (int j = 0; j < 8; ++j) {
    float h = acc[j] * inv + bp[j >> 1];
    r8[j] = 0.5f * h * (1.0f + erff(h * is2));
  }
  float* dst = res + (size_t)t * J + lane * 8;
  *(float4*)dst       = make_float4(r8[0], r8[1], r8[2], r8[3]);
  *(float4*)(dst + 4) = make_float4(r8[4], r8[5], r8[6], r8[7]);
}

// ---------------------------------------------------------------------------
// K4b (tier-2 fallback — round-7 verified): atomic-scatter MFMA GEMM.
// ---------------------------------------------------------------------------
__global__ __launch_bounds__(256)
void k4b_mfma(const unsigned short* __restrict__ xb,
              const unsigned short* __restrict__ bm,
              const float* __restrict__ o_idx, const float* __restrict__ o_scr,
              float* __restrict__ out) {
  const int e  = blockIdx.z;
  const int km = blockIdx.y;
  const int fn = blockIdx.x;
  __shared__ __align__(16) unsigned short As[128 * 64];
  __shared__ __align__(16) unsigned short Bs[128 * 64];
  __shared__ int   tIdx[128];
  __shared__ float wRow[128];
  const int tid = threadIdx.x;
  if (tid < 128) {
    size_t gi = (size_t)e * K + km * 128 + tid;
    tIdx[tid] = (int)o_idx[gi];
    wRow[tid] = o_scr[gi];
  }
  __syncthreads();

  const int lane = tid & 63;
  const int w    = tid >> 6;
  const int wr   = (w & 1) * 64;
  const int wc   = (w >> 1) * 64;
  const int l15  = lane & 15, l4 = lane >> 4;
  const int ls   = lane & 7, lr = lane >> 3;
  const int gch  = ls ^ lr;

  const char* aSrc[4];
  const char* bSrc[4];
  unsigned short* aDst[4];
  unsigned short* bDst[4];
#pragma unroll
  for (int i = 0; i < 4; ++i) {
    int r = w * 32 + i * 8 + lr;
    aSrc[i] = (const char*)xb + (size_t)tIdx[r] * 1024 + gch * 16;
    bSrc[i] = (const char*)bm + ((size_t)e * 512 + fn * 128 + r) * 1024 +
              gch * 16;
    aDst[i] = As + (w * 32 + i * 8) * 64 + lane * 8;
    bDst[i] = Bs + (w * 32 + i * 8) * 64 + lane * 8;
  }

  f32x4 acc[4][4];
#pragma unroll
  for (int m = 0; m < 4; ++m)
#pragma unroll
    for (int n = 0; n < 4; ++n) acc[m][n] = (f32x4){0.f, 0.f, 0.f, 0.f};

  for (int kk = 0; kk < J; kk += 64) {
#pragma unroll
    for (int i = 0; i < 4; ++i) {
      gl16(aSrc[i] + kk * 2, aDst[i]);
      gl16(bSrc[i] + kk * 2, bDst[i]);
    }
    __syncthreads();
#pragma unroll
    for (int kk2 = 0; kk2 < 2; ++kk2) {
      bf16x8 af[4], bfr[4];
#pragma unroll
      for (int m = 0; m < 4; ++m) {
        int r = wr + m * 16 + l15;
        int s = (kk2 * 4 + l4) ^ (r & 7);
        af[m] = *(const bf16x8*)(&As[r * 64 + s * 8]);
      }
#pragma unroll
      for (int n = 0; n < 4; ++n) {
        int cl = wc + n * 16 + l15;
        int s = (kk2 * 4 + l4) ^ (cl & 7);
        bfr[n] = *(const bf16x8*)(&Bs[cl * 64 + s * 8]);
      }
#pragma unroll
      for (int m = 0; m < 4; ++m)
#pragma unroll
        for (int n = 0; n < 4; ++n)
          acc[m][n] = __builtin_amdgcn_mfma_f32_16x16x32_bf16(
              af[m], bfr[n], acc[m][n], 0, 0, 0);
    }
    __syncthreads();
  }

#pragma unroll
  for (int m = 0; m < 4; ++m) {
#pragma unroll
    for (int q = 0; q < 4; ++q) {
      int rl = wr + m * 16 + l4 * 4 + q;
      int t = tIdx[rl];
      float wv = wRow[rl];
      float* dst = out + (size_t)t * J + fn * 128 + wc + l15;
#pragma unroll
      for (int n = 0; n < 4; ++n)
        atomicAdd(dst + n * 16, acc[m][n][q] * wv);
    }
  }
}

// ---------------------------------------------------------------------------
// K5 (tier-2 fallback): res = gelu(out/max(cnt,1)+bias), in place.
// ---------------------------------------------------------------------------
__global__ __launch_bounds__(256)
void k5_final(float* __restrict__ res, const float* __restrict__ cnt,
              const float* __restrict__ bias) {
  const int total4 = BT * J / 4;
  for (int i = blockIdx.x * blockDim.x + threadIdx.x; i < total4;
       i += gridDim.x * blockDim.x) {
    float4 v = reinterpret_cast<float4*>(res)[i];
    int base = i << 2;
    int t = base >> 9;
    int col = base & 511;
    float inv = 1.0f / fmaxf(cnt[t], 1.0f);
    int f0 = col >> 1;
    float b0 = bias[f0], b1 = bias[f0 + 1];
    float h0 = v.x * inv + b0;
    float h1 = v.y * inv + b0;
    float h2 = v.z * inv + b1;
    float h3 = v.w * inv + b1;
    const float is2 = 0.70710678118654752f;
    v.x = 0.5f * h0 * (1.0f + erff(h0 * is2));
    v.y = 0.5f * h1 * (1.0f + erff(h1 * is2));
    v.z = 0.5f * h2 * (1.0f + erff(h2 * is2));
    v.w = 0.5f * h3 * (1.0f + erff(h3 * is2));
    reinterpret_cast<float4*>(res)[i] = v;
  }
}

// ---------------------------------------------------------------------------
extern "C" void kernel_launch(void* const* d_in, const int* in_sizes, int n_in,
                              void* d_out, int out_size, void* d_ws,
                              size_t ws_size, hipStream_t stream) {
  const float* x    = (const float*)d_in[0];
  const float* gw   = (const float*)d_in[1];
  const float* ew   = (const float*)d_in[2];
  const float* bias = (const float*)d_in[3];

  float* out_f = (float*)d_out;
  float* res   = out_f;
  float* o_idx = out_f + OFF_IDX;
  float* o_scr = out_f + OFF_SCR;
  float* o_cnt = out_f + OFF_CNT;

  // scoresT (E x BT floats, 16 MiB) borrows the res region until top-k done.
  float* scoresT = res;

  unsigned short* xb  = (unsigned short*)((char*)d_ws + WS_XB);
  unsigned short* bm  = (unsigned short*)((char*)d_ws + WS_BM);
  unsigned short* yD  = (unsigned short*)((char*)d_ws + WS_YD);
  int*            cur = (int*)((char*)d_ws + WS_CUR);
  int*            slt = (int*)((char*)d_ws + WS_SLOT);

  const bool tier1 = (ws_size >= WS_NEED1);
  const bool tier2 = (ws_size >= WS_NEED2);

  if (tier2) {
    k3a_xbf<<<16384, 256, 0, stream>>>(x, xb);
    k3b_bmat<<<8192, 256, 0, stream>>>(ew, bm);
  }
  hipMemsetAsync(o_cnt, 0, (size_t)BT * sizeof(float), stream);
  if (tier1) hipMemsetAsync(cur, 0, (size_t)BT * sizeof(int), stream);

  k1_scores<<<BT / 64, 256, 0, stream>>>(x, gw, scoresT);
  k2_topk<<<E, 1024, 0, stream>>>(scoresT, o_idx, o_scr, o_cnt,
                                  tier1 ? cur : nullptr,
                                  tier1 ? slt : nullptr);
  if (tier1) {
    k4c_mfma<<<4096, 256, 0, stream>>>(xb, bm, o_idx, o_scr, yD);
    k5g<<<BT / 4, 256, 0, stream>>>(yD, cur, slt, bias, res);
  } else {
    hipMemsetAsync(res, 0, (size_t)BT * J * sizeof(float), stream);
    k4b_mfma<<<dim3(4, 16, E), 256, 0, stream>>>(xb, bm, o_idx, o_scr, res);
    k5_final<<<8192, 256, 0, stream>>>(res, o_cnt, bias);
  }
}